// Round 6
// baseline (255.093 us; speedup 1.0000x reference)
//
#include <hip/hip_runtime.h>
#include <cstdint>
#include <cstddef>

// MultiHeadAttention forward, MI355X (round 6).
// cvt_all -> qkv_gemm (fused 3-way, 512-thread blocks, LDS double-buffer with
// single barrier per K-step, XCD panel remap) -> flash-attn -> o_gemm.
// Attn: 32x32x16 MFMA, swapped QK^T, no-max softmax, XCD remap (unchanged).
// B=4, S=2048, D=1024, H=16, dh=64.

typedef unsigned short u16;
typedef unsigned u32;
typedef short short8 __attribute__((ext_vector_type(8)));
typedef __bf16 bf16x8 __attribute__((ext_vector_type(8)));
typedef float f32x4 __attribute__((ext_vector_type(4)));
typedef float f32x16 __attribute__((ext_vector_type(16)));
typedef unsigned short u16x4 __attribute__((ext_vector_type(4)));
typedef unsigned u32x2 __attribute__((ext_vector_type(2)));
typedef unsigned u32x4 __attribute__((ext_vector_type(4)));
typedef int iv2 __attribute__((ext_vector_type(2)));

__device__ __forceinline__ u16 f2bf(float f) {
  unsigned u = __builtin_bit_cast(unsigned, f);
  u += 0x7fffu + ((u >> 16) & 1u);   // RTNE
  return (u16)(u >> 16);
}
__device__ __forceinline__ bf16x8 bc8(short8 v) { return __builtin_bit_cast(bf16x8, v); }
__device__ __forceinline__ u32 pk_bf16(float a, float b) {
  u32 r;
  asm("v_cvt_pk_bf16_f32 %0, %1, %2" : "=v"(r) : "v"(a), "v"(b));
  return r;  // low16 = bf16(a), high16 = bf16(b)
}
__device__ __forceinline__ void gload16(const u16* g, u16* l) {
  __builtin_amdgcn_global_load_lds((const __attribute__((address_space(1))) void*)g,
                                   (__attribute__((address_space(3))) void*)l, 16, 0, 0);
}

// ---------------- fused fp32 -> bf16 for all 7 tensors ----------------
// regions (f32x4 units): 3 activations of 2^21, then 4 weights of 2^18.
__global__ __launch_bounds__(256) void cvt_all(const float* __restrict__ q,
                                               const float* __restrict__ k,
                                               const float* __restrict__ v,
                                               const float* __restrict__ wq,
                                               const float* __restrict__ wk,
                                               const float* __restrict__ wv,
                                               const float* __restrict__ wo,
                                               u16* __restrict__ xq, u16* __restrict__ xk,
                                               u16* __restrict__ xv, u16* __restrict__ wqb,
                                               u16* __restrict__ wkb, u16* __restrict__ wvb,
                                               u16* __restrict__ wob) {
  const size_t i4 = (size_t)blockIdx.x * 256 + threadIdx.x;
  const size_t A4 = 1ull << 21, W4 = 1ull << 18;
  const float* s;
  u16* d;
  size_t off;
  if (i4 < 3 * A4) {
    const int r = (int)(i4 >> 21);
    off = i4 & (A4 - 1);
    s = r == 0 ? q : (r == 1 ? k : v);
    d = r == 0 ? xq : (r == 1 ? xk : xv);
  } else {
    const size_t t = i4 - 3 * A4;
    const int r = (int)(t >> 18);
    off = t & (W4 - 1);
    s = r == 0 ? wq : (r == 1 ? wk : (r == 2 ? wv : wo));
    d = r == 0 ? wqb : (r == 1 ? wkb : (r == 2 ? wvb : wob));
  }
  const f32x4 a = ((const f32x4*)s)[off];
  u32x2 o = {pk_bf16(a[0], a[1]), pk_bf16(a[2], a[3])};
  ((u32x2*)d)[off] = o;
}

// ---------------- GEMM core: C[M,N] = A[M,K] @ B[N,K]^T + bias, *oscale ----
// 512 threads = 8 waves (4M x 2N, 32x64 out each). 128x128 tile, BK=32.
// LDS double-buffered (2 x (8KB A + 8KB B)); stage next tile via
// global_load_lds BEFORE reading current; ONE __syncthreads per K-step
// (its vmcnt(0) drain covers the stage writes of all waves).
// XCD remap: xp=lin>>6, yp=lin&63 -> all 8 blocks sharing an A panel (same yp)
// sit on xcd = yp%8 -> A fetched once per panel.
// mode: 0 = fp32 row-major out, 1 = bf16 row-major, 2 = bf16 per-head
// transposed (row -> out[((row>>11)*1024 + n)*2048 + (row&2047)]) for V.
__device__ __forceinline__ void gemm_core(u16* lds, const u16* __restrict__ A,
                                          const u16* __restrict__ Bw,
                                          const float* __restrict__ bias,
                                          void* __restrict__ C, int mode, float oscale) {
  constexpr int K = 1024, N = 1024;
  const int tid = threadIdx.x;
  const int w = tid >> 6, l = tid & 63, g = l >> 4, m = l & 15;
  const int wr = w & 3, wc = w >> 2;
  const int lin = blockIdx.x + 8 * blockIdx.y;  // gridDim.x == 8
  const int xp = lin >> 6, yp = lin & 63;
  const int m0 = yp * 128, n0 = xp * 128;

  // staging: wave w owns chunk w (16 rows x 32 cols) of both A and B tiles.
  const int srow = w * 16 + (l >> 2);
  const int scol = (l & 3) * 8;
  const u16* gA = A + (size_t)(m0 + srow) * K + scol;
  const u16* gB = Bw + (size_t)(n0 + srow) * K + scol;
  // buffers: buf i at lds + i*16384 (u16 units: i*8192); A first 4096, B next.
  u16* lA[2] = {lds + 0, lds + 8192};
  u16* lB[2] = {lds + 4096, lds + 12288};
  u16* dstA[2] = {lA[0] + w * 512, lA[1] + w * 512};
  u16* dstB[2] = {lB[0] + w * 512, lB[1] + w * 512};

  f32x4 acc[2][4];
  const f32x4 z = {0.f, 0.f, 0.f, 0.f};
#pragma unroll
  for (int i = 0; i < 2; ++i)
#pragma unroll
    for (int j = 0; j < 4; ++j) acc[i][j] = z;

  gload16(gA, dstA[0]);
  gload16(gB, dstB[0]);
  __syncthreads();

  for (int kk = 0; kk < 32; ++kk) {
    const int cur = kk & 1, nxt = cur ^ 1;
    if (kk + 1 < 32) {  // stage next tile into the other buffer (no wait)
      const int ko = (kk + 1) * 32;
      gload16(gA + ko, dstA[nxt]);
      gload16(gB + ko, dstB[nxt]);
    }
    bf16x8 af[2], bfr[4];
#pragma unroll
    for (int i = 0; i < 2; ++i)
      af[i] = bc8(*(const short8*)(lA[cur] + (wr * 32 + i * 16 + m) * 32 + g * 8));
#pragma unroll
    for (int j = 0; j < 4; ++j)
      bfr[j] = bc8(*(const short8*)(lB[cur] + (wc * 64 + j * 16 + m) * 32 + g * 8));
#pragma unroll
    for (int i = 0; i < 2; ++i)
#pragma unroll
      for (int j = 0; j < 4; ++j)
        acc[i][j] = __builtin_amdgcn_mfma_f32_16x16x32_bf16(af[i], bfr[j], acc[i][j], 0, 0, 0);
    __syncthreads();  // drains vmcnt(0)+lgkmcnt(0): stage complete, reads consumed
  }

  float bv[4];
#pragma unroll
  for (int j = 0; j < 4; ++j) bv[j] = bias[n0 + wc * 64 + j * 16 + m];

  if (mode == 2) {
#pragma unroll
    for (int i = 0; i < 2; ++i)
#pragma unroll
      for (int j = 0; j < 4; ++j) {
        const int row0 = m0 + wr * 32 + i * 16 + g * 4;
        const int col = n0 + wc * 64 + j * 16 + m;
        u16x4 o;
#pragma unroll
        for (int r = 0; r < 4; ++r) o[r] = f2bf((acc[i][j][r] + bv[j]) * oscale);
        *(u16x4*)((u16*)C + ((size_t)(row0 >> 11) * 1024 + col) * 2048 + (row0 & 2047)) = o;
      }
  } else {
#pragma unroll
    for (int i = 0; i < 2; ++i) {
#pragma unroll
      for (int r = 0; r < 4; ++r) {
        const int row = m0 + wr * 32 + i * 16 + g * 4 + r;
#pragma unroll
        for (int j = 0; j < 4; ++j) {
          const int col = n0 + wc * 64 + j * 16 + m;
          const float v = (acc[i][j][r] + bv[j]) * oscale;
          if (mode == 0)
            ((float*)C)[(size_t)row * N + col] = v;
          else
            ((u16*)C)[(size_t)row * N + col] = f2bf(v);
        }
      }
    }
  }
}

// fused Q/K/V projections; z selects. Q output pre-scaled by SC.
__global__ __launch_bounds__(512, 2) void qkv_gemm(const u16* __restrict__ xq,
                                                   const u16* __restrict__ xk,
                                                   const u16* __restrict__ xv,
                                                   const u16* __restrict__ wqb,
                                                   const u16* __restrict__ wkb,
                                                   const u16* __restrict__ wvb,
                                                   const float* __restrict__ bq,
                                                   const float* __restrict__ bk,
                                                   const float* __restrict__ bv,
                                                   u16* __restrict__ Qp, u16* __restrict__ Kp,
                                                   u16* __restrict__ Vt, float SC) {
  __shared__ alignas(16) u16 lds[16384];  // 32KB: 2 buffers x (A 8KB + B 8KB)
  const int z = blockIdx.z;
  const u16* A = z == 0 ? xq : (z == 1 ? xk : xv);
  const u16* W = z == 0 ? wqb : (z == 1 ? wkb : wvb);
  const float* bi = z == 0 ? bq : (z == 1 ? bk : bv);
  void* C = z == 0 ? (void*)Qp : (z == 1 ? (void*)Kp : (void*)Vt);
  gemm_core(lds, A, W, bi, C, z == 2 ? 2 : 1, z == 0 ? SC : 1.f);
}

__global__ __launch_bounds__(512, 2) void o_gemm(const u16* __restrict__ Xa,
                                                 const u16* __restrict__ wob,
                                                 const float* __restrict__ bo,
                                                 float* __restrict__ out) {
  __shared__ alignas(16) u16 lds[16384];
  gemm_core(lds, Xa, wob, bo, out, 0, 1.f);
}

// ---------------- flash attention (32x32 MFMA, no-max softmax) ------------
// grid (S/256, B*H); block 512 = 8 waves; wave handles 32 q-rows; KV tile 64.
// XCD-aware remap: all 8 q-chunks of one head land on one XCD's L2.
__global__ __launch_bounds__(512, 4) void attn_fwd(const u16* __restrict__ Q,
                                                   const u16* __restrict__ Kp,
                                                   const u16* __restrict__ Vt,
                                                   u16* __restrict__ Xa) {
  __shared__ alignas(16) u16 kl[64][72];   // K tile [k][d]
  __shared__ alignas(16) u16 vl[64][72];   // V^T tile [d][k]
  const int tid = threadIdx.x;
  const int l = tid & 63, w = tid >> 6;
  const int q32 = l & 31, hi = l >> 5;
  const int lin = blockIdx.x + 8 * blockIdx.y;
  const int xp = lin >> 6, yp = lin & 63;  // yp%8 == lin%8 -> same XCD per head
  const int b = yp >> 4, h = yp & 15;
  const int q0 = xp * 256 + w * 32;

  // Q B-frags: lane holds col q=q32, k-rows d = ds*16 + hi*8 + j
  bf16x8 qf[4];
  const size_t qrow = (size_t)b * 2048 + q0 + q32;
#pragma unroll
  for (int ds = 0; ds < 4; ++ds)
    qf[ds] = bc8(*(const short8*)(Q + qrow * 1024 + h * 64 + ds * 16 + hi * 8));

  f32x16 of[2] = {{}, {}};
  float l0 = 0.f, l1 = 0.f, l2 = 0.f, l3 = 0.f;

  const int sr = tid >> 3;         // staging row 0..63
  const int sc8 = (tid & 7) * 8;   // staging col (u16)
  const u16* Kb = Kp + (size_t)b * 2048 * 1024 + h * 64;
  const u16* Vb = Vt + (size_t)yp * 64 * 2048;

  short8 rk = *(const short8*)(Kb + (size_t)sr * 1024 + sc8);
  short8 rv = *(const short8*)(Vb + (size_t)sr * 2048 + sc8);

  for (int kt = 0; kt < 32; ++kt) {
    *(short8*)(&kl[sr][sc8]) = rk;
    *(short8*)(&vl[sr][sc8]) = rv;
    __syncthreads();
    if (kt + 1 < 32) {
      rk = *(const short8*)(Kb + (size_t)((kt + 1) * 64 + sr) * 1024 + sc8);
      rv = *(const short8*)(Vb + (size_t)sr * 2048 + (kt + 1) * 64 + sc8);
    }

#pragma unroll
    for (int kt2 = 0; kt2 < 2; ++kt2) {
      // S^T tile (32k x 32q)
      f32x16 st = {};
#pragma unroll
      for (int ds = 0; ds < 4; ++ds) {
        const bf16x8 kf = bc8(*(const short8*)(&kl[kt2 * 32 + q32][ds * 16 + hi * 8]));
        st = __builtin_amdgcn_mfma_f32_32x32x16_bf16(kf, qf[ds], st, 0, 0, 0);
      }
      // P = exp2(S); row-sum accumulates in-lane (no max subtraction)
      float p[16];
#pragma unroll
      for (int r = 0; r < 16; ++r) p[r] = __builtin_amdgcn_exp2f(st[r]);
      l0 += (p[0] + p[1]) + (p[2] + p[3]);
      l1 += (p[4] + p[5]) + (p[6] + p[7]);
      l2 += (p[8] + p[9]) + (p[10] + p[11]);
      l3 += (p[12] + p[13]) + (p[14] + p[15]);
      // P^T B-frags: B[j] = C-reg[4*(2s+hi)+(j&3)] of lane (q, j>>2)
#pragma unroll
      for (int s = 0; s < 2; ++s) {
        int X0 = (int)pk_bf16(p[8 * s + 0], p[8 * s + 1]);
        int X1 = (int)pk_bf16(p[8 * s + 2], p[8 * s + 3]);
        int Y0 = (int)pk_bf16(p[8 * s + 4], p[8 * s + 5]);
        int Y1 = (int)pk_bf16(p[8 * s + 6], p[8 * s + 7]);
        iv2 r0 = __builtin_amdgcn_permlane32_swap(X0, Y0, false, false);
        iv2 r1 = __builtin_amdgcn_permlane32_swap(X1, Y1, false, false);
        u32x4 bw = {(u32)r0[0], (u32)r1[0], (u32)r0[1], (u32)r1[1]};
        const bf16x8 pb = __builtin_bit_cast(bf16x8, bw);
        const int ks = kt2 * 2 + s;
#pragma unroll
        for (int dt = 0; dt < 2; ++dt) {
          const bf16x8 vf = bc8(*(const short8*)(&vl[dt * 32 + q32][ks * 16 + hi * 8]));
          of[dt] = __builtin_amdgcn_mfma_f32_32x32x16_bf16(vf, pb, of[dt], 0, 0, 0);
        }
      }
    }
    __syncthreads();
  }

  float lo = (l0 + l1) + (l2 + l3);
  lo += __shfl_xor(lo, 32, 64);
  const float inv = 1.0f / lo;

  // O^T: lane holds col q=q32, rows d = dt*32 + rg*8 + hi*4 + (r&3)
#pragma unroll
  for (int dt = 0; dt < 2; ++dt)
#pragma unroll
    for (int rg = 0; rg < 4; ++rg) {
      u32x2 o2;
      o2[0] = pk_bf16(of[dt][4 * rg + 0] * inv, of[dt][4 * rg + 1] * inv);
      o2[1] = pk_bf16(of[dt][4 * rg + 2] * inv, of[dt][4 * rg + 3] * inv);
      *(u32x2*)(Xa + qrow * 1024 + h * 64 + dt * 32 + rg * 8 + hi * 4) = o2;
    }
}

// ---------------- launch ----------------
extern "C" void kernel_launch(void* const* d_in, const int* in_sizes, int n_in,
                              void* d_out, int out_size, void* d_ws, size_t ws_size,
                              hipStream_t stream) {
  const float* q  = (const float*)d_in[0];
  const float* k  = (const float*)d_in[1];
  const float* v  = (const float*)d_in[2];
  const float* Wq = (const float*)d_in[3];
  const float* bq = (const float*)d_in[4];
  const float* Wk = (const float*)d_in[5];
  const float* bk = (const float*)d_in[6];
  const float* Wv = (const float*)d_in[7];
  const float* bv = (const float*)d_in[8];
  const float* Wo = (const float*)d_in[9];
  const float* bo = (const float*)d_in[10];

  char* ws = (char*)d_ws;
  const size_t MB = 1024ull * 1024ull;
  u16* wqb = (u16*)(ws + 0 * MB);
  u16* wkb = (u16*)(ws + 2 * MB);
  u16* wvb = (u16*)(ws + 4 * MB);
  u16* wob = (u16*)(ws + 6 * MB);
  u16* xq  = (u16*)(ws + 8 * MB);   // 16MB; reused as Xa after qkv_gemm
  u16* xk  = (u16*)(ws + 24 * MB);  // 16MB
  u16* xv  = (u16*)(ws + 40 * MB);  // 16MB
  u16* Qp  = (u16*)(ws + 56 * MB);  // 16MB, pre-scaled by SC
  u16* Kp  = (u16*)(ws + 72 * MB);  // 16MB
  u16* Vt  = xk;                    // hmm: xk consumed by z=1 while z=2 writes Vt
  u16* Xa  = xq;                    // written by attn (xq dead by then)

  // NOTE: Vt must NOT alias xk: z=1 (K proj) reads xk while z=2 writes Vt
  // concurrently in the same fused launch. Use a dedicated region instead.
  Vt = (u16*)(ws + 88 * MB);        // 16MB, dedicated

  cvt_all<<<28672, 256, 0, stream>>>(q, k, v, Wq, Wk, Wv, Wo,
                                     xq, xk, xv, wqb, wkb, wvb, wob);

  const float SC = 0.125f * 1.44269504f;  // head scale * log2(e)
  qkv_gemm<<<dim3(8, 64, 3), 512, 0, stream>>>(xq, xk, xv, wqb, wkb, wvb,
                                               bq, bk, bv, Qp, Kp, Vt, SC);

  attn_fwd<<<dim3(8, 64), 512, 0, stream>>>(Qp, Kp, Vt, Xa);

  o_gemm<<<dim3(8, 64), 512, 0, stream>>>(Xa, wob, bo, (float*)d_out);
}

// Round 7
// 192.445 us; speedup vs baseline: 1.3255x; 1.3255x over previous
//
#include <hip/hip_runtime.h>
#include <cstdint>
#include <cstddef>

// MultiHeadAttention forward, MI355X (round 7).
// cvt_all -> qkv_gemm (128x256 tile, BK=32, 3-buffer LDS pipeline with counted
// vmcnt(6), 4 phases/tile, setprio around MFMA) -> flash-attn -> o_gemm.
// Attn: 32x32x16 MFMA, swapped QK^T, no-max softmax, XCD remap (unchanged).
// B=4, S=2048, D=1024, H=16, dh=64.

typedef unsigned short u16;
typedef unsigned u32;
typedef short short8 __attribute__((ext_vector_type(8)));
typedef __bf16 bf16x8 __attribute__((ext_vector_type(8)));
typedef float f32x4 __attribute__((ext_vector_type(4)));
typedef float f32x16 __attribute__((ext_vector_type(16)));
typedef unsigned short u16x4 __attribute__((ext_vector_type(4)));
typedef unsigned u32x2 __attribute__((ext_vector_type(2)));
typedef unsigned u32x4 __attribute__((ext_vector_type(4)));
typedef int iv2 __attribute__((ext_vector_type(2)));

__device__ __forceinline__ u16 f2bf(float f) {
  unsigned u = __builtin_bit_cast(unsigned, f);
  u += 0x7fffu + ((u >> 16) & 1u);   // RTNE
  return (u16)(u >> 16);
}
__device__ __forceinline__ bf16x8 bc8(short8 v) { return __builtin_bit_cast(bf16x8, v); }
__device__ __forceinline__ u32 pk_bf16(float a, float b) {
  u32 r;
  asm("v_cvt_pk_bf16_f32 %0, %1, %2" : "=v"(r) : "v"(a), "v"(b));
  return r;  // low16 = bf16(a), high16 = bf16(b)
}
__device__ __forceinline__ void gload16(const u16* g, u16* l) {
  __builtin_amdgcn_global_load_lds((const __attribute__((address_space(1))) void*)g,
                                   (__attribute__((address_space(3))) void*)l, 16, 0, 0);
}

// ---------------- fused fp32 -> bf16 for all 7 tensors ----------------
__global__ __launch_bounds__(256) void cvt_all(const float* __restrict__ q,
                                               const float* __restrict__ k,
                                               const float* __restrict__ v,
                                               const float* __restrict__ wq,
                                               const float* __restrict__ wk,
                                               const float* __restrict__ wv,
                                               const float* __restrict__ wo,
                                               u16* __restrict__ xq, u16* __restrict__ xk,
                                               u16* __restrict__ xv, u16* __restrict__ wqb,
                                               u16* __restrict__ wkb, u16* __restrict__ wvb,
                                               u16* __restrict__ wob) {
  const size_t i4 = (size_t)blockIdx.x * 256 + threadIdx.x;
  const size_t A4 = 1ull << 21, W4 = 1ull << 18;
  const float* s;
  u16* d;
  size_t off;
  if (i4 < 3 * A4) {
    const int r = (int)(i4 >> 21);
    off = i4 & (A4 - 1);
    s = r == 0 ? q : (r == 1 ? k : v);
    d = r == 0 ? xq : (r == 1 ? xk : xv);
  } else {
    const size_t t = i4 - 3 * A4;
    const int r = (int)(t >> 18);
    off = t & (W4 - 1);
    s = r == 0 ? wq : (r == 1 ? wk : (r == 2 ? wv : wo));
    d = r == 0 ? wqb : (r == 1 ? wkb : (r == 2 ? wvb : wob));
  }
  const f32x4 a = ((const f32x4*)s)[off];
  u32x2 o = {pk_bf16(a[0], a[1]), pk_bf16(a[2], a[3])};
  ((u32x2*)d)[off] = o;
}

// ---------------- pipelined GEMM core ----------------
// C[M=8192, N=1024] = A[M,1024] @ B[N,1024]^T + bias, *oscale.
// Block tile 128(M) x 256(N), BK=32. 256 threads = 4 waves; wave (wr, wc)
// owns a 64x128 sub-tile: acc[4][8] 16x16 frags (43 flops per LDS byte read).
// 3 LDS buffers of 24KB (A 8KB + B 16KB): compute buf[t%3], tile t+1 in
// flight, stage tile t+2 into buf[(t+2)%3] -> no overwrite race, and the
// per-tile boundary is s_waitcnt vmcnt(6) (counted, never 0) + raw s_barrier.
// 4 phases/tile: {ds_read frags | issue stage -> barrier -> 8 MFMA -> barrier}.
__device__ __forceinline__ bf16x8 ldf(const u16* buf, int row, int g) {
  return bc8(*(const short8*)(buf + row * 32 + g * 8));
}

__device__ __forceinline__ void gemm_core(u16* lds, const u16* __restrict__ A,
                                          const u16* __restrict__ Bw,
                                          const float* __restrict__ bias,
                                          void* __restrict__ C, int mode, float oscale) {
  const int t = threadIdx.x;
  const int w = t >> 6, l = t & 63, g = l >> 4, m = l & 15;
  const int wr = w >> 1, wc = w & 1;
  const int m0 = blockIdx.x * 128, n0 = blockIdx.y * 256;
  const u16* gA = A + (size_t)m0 * 1024;
  const u16* gB = Bw + (size_t)n0 * 1024;

  f32x4 acc[4][8];
  const f32x4 z = {0.f, 0.f, 0.f, 0.f};
#pragma unroll
  for (int i = 0; i < 4; ++i)
#pragma unroll
    for (int j = 0; j < 8; ++j) acc[i][j] = z;

  // prologue: stage tiles 0 and 1 fully (6 ops each), then wait for tile 0.
#pragma unroll
  for (int tt = 0; tt < 2; ++tt) {
    u16* sA = lds + tt * 12288;
    u16* sB = sA + 4096;
    const int ko = tt * 32;
#pragma unroll
    for (int r = 0; r < 2; ++r) {
      const int c = r * 256 + t;
      gload16(gA + (size_t)(c >> 2) * 1024 + (c & 3) * 8 + ko, sA + c * 8);
    }
#pragma unroll
    for (int r = 0; r < 4; ++r) {
      const int c = r * 256 + t;
      gload16(gB + (size_t)(c >> 2) * 1024 + (c & 3) * 8 + ko, sB + c * 8);
    }
  }
  asm volatile("s_waitcnt vmcnt(6)" ::: "memory");
  __builtin_amdgcn_s_barrier();

  bf16x8 af[4], bfr[8];
  int cb = 0;  // tt % 3
  for (int tt = 0; tt < 32; ++tt) {
    u16* bA = lds + cb * 12288;
    u16* bB = bA + 4096;
    const int sbi = (cb == 0) ? 2 : cb - 1;  // (tt+2) % 3
    u16* sA = lds + sbi * 12288;
    u16* sB = sA + 4096;
    const int ko = (tt + 2) * 32;
    const bool st = tt < 30;

    // ---- phase 0: read A0-1 + B0-3, stage A(t+2), mfma i{0,1} x j{0..3}
    af[0] = ldf(bA, wr * 64 + m, g);
    af[1] = ldf(bA, wr * 64 + 16 + m, g);
#pragma unroll
    for (int j = 0; j < 4; ++j) bfr[j] = ldf(bB, wc * 128 + j * 16 + m, g);
    if (st) {
#pragma unroll
      for (int r = 0; r < 2; ++r) {
        const int c = r * 256 + t;
        gload16(gA + (size_t)(c >> 2) * 1024 + (c & 3) * 8 + ko, sA + c * 8);
      }
    }
    __builtin_amdgcn_s_barrier();
    __builtin_amdgcn_s_setprio(1);
#pragma unroll
    for (int i = 0; i < 2; ++i)
#pragma unroll
      for (int j = 0; j < 4; ++j)
        acc[i][j] = __builtin_amdgcn_mfma_f32_16x16x32_bf16(af[i], bfr[j], acc[i][j], 0, 0, 0);
    __builtin_amdgcn_s_setprio(0);
    __builtin_amdgcn_s_barrier();

    // ---- phase 1: read B4-7, stage B(t+2) rounds 0-1, mfma i{0,1} x j{4..7}
#pragma unroll
    for (int j = 4; j < 8; ++j) bfr[j] = ldf(bB, wc * 128 + j * 16 + m, g);
    if (st) {
#pragma unroll
      for (int r = 0; r < 2; ++r) {
        const int c = r * 256 + t;
        gload16(gB + (size_t)(c >> 2) * 1024 + (c & 3) * 8 + ko, sB + c * 8);
      }
    }
    __builtin_amdgcn_s_barrier();
    __builtin_amdgcn_s_setprio(1);
#pragma unroll
    for (int i = 0; i < 2; ++i)
#pragma unroll
      for (int j = 4; j < 8; ++j)
        acc[i][j] = __builtin_amdgcn_mfma_f32_16x16x32_bf16(af[i], bfr[j], acc[i][j], 0, 0, 0);
    __builtin_amdgcn_s_setprio(0);
    __builtin_amdgcn_s_barrier();

    // ---- phase 2: read A2-3, stage B(t+2) rounds 2-3, mfma i{2,3} x j{0..3}
    af[2] = ldf(bA, wr * 64 + 32 + m, g);
    af[3] = ldf(bA, wr * 64 + 48 + m, g);
    if (st) {
#pragma unroll
      for (int r = 2; r < 4; ++r) {
        const int c = r * 256 + t;
        gload16(gB + (size_t)(c >> 2) * 1024 + (c & 3) * 8 + ko, sB + c * 8);
      }
    }
    __builtin_amdgcn_s_barrier();
    __builtin_amdgcn_s_setprio(1);
#pragma unroll
    for (int i = 2; i < 4; ++i)
#pragma unroll
      for (int j = 0; j < 4; ++j)
        acc[i][j] = __builtin_amdgcn_mfma_f32_16x16x32_bf16(af[i], bfr[j], acc[i][j], 0, 0, 0);
    __builtin_amdgcn_s_setprio(0);
    __builtin_amdgcn_s_barrier();

    // ---- phase 3: mfma i{2,3} x j{4..7}; tile boundary: counted vmcnt
    __builtin_amdgcn_s_setprio(1);
#pragma unroll
    for (int i = 2; i < 4; ++i)
#pragma unroll
      for (int j = 4; j < 8; ++j)
        acc[i][j] = __builtin_amdgcn_mfma_f32_16x16x32_bf16(af[i], bfr[j], acc[i][j], 0, 0, 0);
    __builtin_amdgcn_s_setprio(0);
    if (tt < 30)
      asm volatile("s_waitcnt vmcnt(6)" ::: "memory");  // tile t+1 resident
    else
      asm volatile("s_waitcnt vmcnt(0)" ::: "memory");  // tail drain
    __builtin_amdgcn_s_barrier();
    cb = (cb == 2) ? 0 : cb + 1;
  }

  // ---- epilogue ----
  float bv[8];
#pragma unroll
  for (int j = 0; j < 8; ++j) bv[j] = bias[n0 + wc * 128 + j * 16 + m];

  if (mode == 2) {
#pragma unroll
    for (int i = 0; i < 4; ++i)
#pragma unroll
      for (int j = 0; j < 8; ++j) {
        const int row0 = m0 + wr * 64 + i * 16 + g * 4;
        const int col = n0 + wc * 128 + j * 16 + m;
        u16x4 o;
#pragma unroll
        for (int r = 0; r < 4; ++r) o[r] = f2bf((acc[i][j][r] + bv[j]) * oscale);
        *(u16x4*)((u16*)C + ((size_t)(row0 >> 11) * 1024 + col) * 2048 + (row0 & 2047)) = o;
      }
  } else {
#pragma unroll
    for (int i = 0; i < 4; ++i) {
#pragma unroll
      for (int r = 0; r < 4; ++r) {
        const int row = m0 + wr * 64 + i * 16 + g * 4 + r;
#pragma unroll
        for (int j = 0; j < 8; ++j) {
          const int col = n0 + wc * 128 + j * 16 + m;
          const float v = (acc[i][j][r] + bv[j]) * oscale;
          if (mode == 0)
            ((float*)C)[(size_t)row * 1024 + col] = v;
          else
            ((u16*)C)[(size_t)row * 1024 + col] = f2bf(v);
        }
      }
    }
  }
}

// fused Q/K/V projections; z selects. Q output pre-scaled by SC.
__global__ __launch_bounds__(256, 2) void qkv_gemm(const u16* __restrict__ xq,
                                                   const u16* __restrict__ xk,
                                                   const u16* __restrict__ xv,
                                                   const u16* __restrict__ wqb,
                                                   const u16* __restrict__ wkb,
                                                   const u16* __restrict__ wvb,
                                                   const float* __restrict__ bq,
                                                   const float* __restrict__ bk,
                                                   const float* __restrict__ bv,
                                                   u16* __restrict__ Qp, u16* __restrict__ Kp,
                                                   u16* __restrict__ Vt, float SC) {
  __shared__ alignas(16) u16 lds[36864];  // 72KB: 3 x (A 8KB + B 16KB)
  const int z = blockIdx.z;
  const u16* A = z == 0 ? xq : (z == 1 ? xk : xv);
  const u16* W = z == 0 ? wqb : (z == 1 ? wkb : wvb);
  const float* bi = z == 0 ? bq : (z == 1 ? bk : bv);
  void* C = z == 0 ? (void*)Qp : (z == 1 ? (void*)Kp : (void*)Vt);
  gemm_core(lds, A, W, bi, C, z == 2 ? 2 : 1, z == 0 ? SC : 1.f);
}

__global__ __launch_bounds__(256, 2) void o_gemm(const u16* __restrict__ Xa,
                                                 const u16* __restrict__ wob,
                                                 const float* __restrict__ bo,
                                                 float* __restrict__ out) {
  __shared__ alignas(16) u16 lds[36864];
  gemm_core(lds, Xa, wob, bo, out, 0, 1.f);
}

// ---------------- flash attention (32x32 MFMA, no-max softmax) ------------
// grid (S/256, B*H); block 512 = 8 waves; wave handles 32 q-rows; KV tile 64.
// XCD-aware remap: all 8 q-chunks of one head land on one XCD's L2.
__global__ __launch_bounds__(512, 4) void attn_fwd(const u16* __restrict__ Q,
                                                   const u16* __restrict__ Kp,
                                                   const u16* __restrict__ Vt,
                                                   u16* __restrict__ Xa) {
  __shared__ alignas(16) u16 kl[64][72];   // K tile [k][d]
  __shared__ alignas(16) u16 vl[64][72];   // V^T tile [d][k]
  const int tid = threadIdx.x;
  const int l = tid & 63, w = tid >> 6;
  const int q32 = l & 31, hi = l >> 5;
  const int lin = blockIdx.x + 8 * blockIdx.y;
  const int xp = lin >> 6, yp = lin & 63;  // yp%8 == lin%8 -> same XCD per head
  const int b = yp >> 4, h = yp & 15;
  const int q0 = xp * 256 + w * 32;

  // Q B-frags: lane holds col q=q32, k-rows d = ds*16 + hi*8 + j
  bf16x8 qf[4];
  const size_t qrow = (size_t)b * 2048 + q0 + q32;
#pragma unroll
  for (int ds = 0; ds < 4; ++ds)
    qf[ds] = bc8(*(const short8*)(Q + qrow * 1024 + h * 64 + ds * 16 + hi * 8));

  f32x16 of[2] = {{}, {}};
  float l0 = 0.f, l1 = 0.f, l2 = 0.f, l3 = 0.f;

  const int sr = tid >> 3;         // staging row 0..63
  const int sc8 = (tid & 7) * 8;   // staging col (u16)
  const u16* Kb = Kp + (size_t)b * 2048 * 1024 + h * 64;
  const u16* Vb = Vt + (size_t)yp * 64 * 2048;

  short8 rk = *(const short8*)(Kb + (size_t)sr * 1024 + sc8);
  short8 rv = *(const short8*)(Vb + (size_t)sr * 2048 + sc8);

  for (int kt = 0; kt < 32; ++kt) {
    *(short8*)(&kl[sr][sc8]) = rk;
    *(short8*)(&vl[sr][sc8]) = rv;
    __syncthreads();
    if (kt + 1 < 32) {
      rk = *(const short8*)(Kb + (size_t)((kt + 1) * 64 + sr) * 1024 + sc8);
      rv = *(const short8*)(Vb + (size_t)sr * 2048 + (kt + 1) * 64 + sc8);
    }

#pragma unroll
    for (int kt2 = 0; kt2 < 2; ++kt2) {
      // S^T tile (32k x 32q)
      f32x16 st = {};
#pragma unroll
      for (int ds = 0; ds < 4; ++ds) {
        const bf16x8 kf = bc8(*(const short8*)(&kl[kt2 * 32 + q32][ds * 16 + hi * 8]));
        st = __builtin_amdgcn_mfma_f32_32x32x16_bf16(kf, qf[ds], st, 0, 0, 0);
      }
      // P = exp2(S); row-sum accumulates in-lane (no max subtraction)
      float p[16];
#pragma unroll
      for (int r = 0; r < 16; ++r) p[r] = __builtin_amdgcn_exp2f(st[r]);
      l0 += (p[0] + p[1]) + (p[2] + p[3]);
      l1 += (p[4] + p[5]) + (p[6] + p[7]);
      l2 += (p[8] + p[9]) + (p[10] + p[11]);
      l3 += (p[12] + p[13]) + (p[14] + p[15]);
      // P^T B-frags: B[j] = C-reg[4*(2s+hi)+(j&3)] of lane (q, j>>2)
#pragma unroll
      for (int s = 0; s < 2; ++s) {
        int X0 = (int)pk_bf16(p[8 * s + 0], p[8 * s + 1]);
        int X1 = (int)pk_bf16(p[8 * s + 2], p[8 * s + 3]);
        int Y0 = (int)pk_bf16(p[8 * s + 4], p[8 * s + 5]);
        int Y1 = (int)pk_bf16(p[8 * s + 6], p[8 * s + 7]);
        iv2 r0 = __builtin_amdgcn_permlane32_swap(X0, Y0, false, false);
        iv2 r1 = __builtin_amdgcn_permlane32_swap(X1, Y1, false, false);
        u32x4 bw = {(u32)r0[0], (u32)r1[0], (u32)r0[1], (u32)r1[1]};
        const bf16x8 pb = __builtin_bit_cast(bf16x8, bw);
        const int ks = kt2 * 2 + s;
#pragma unroll
        for (int dt = 0; dt < 2; ++dt) {
          const bf16x8 vf = bc8(*(const short8*)(&vl[dt * 32 + q32][ks * 16 + hi * 8]));
          of[dt] = __builtin_amdgcn_mfma_f32_32x32x16_bf16(vf, pb, of[dt], 0, 0, 0);
        }
      }
    }
    __syncthreads();
  }

  float lo = (l0 + l1) + (l2 + l3);
  lo += __shfl_xor(lo, 32, 64);
  const float inv = 1.0f / lo;

  // O^T: lane holds col q=q32, rows d = dt*32 + rg*8 + hi*4 + (r&3)
#pragma unroll
  for (int dt = 0; dt < 2; ++dt)
#pragma unroll
    for (int rg = 0; rg < 4; ++rg) {
      u32x2 o2;
      o2[0] = pk_bf16(of[dt][4 * rg + 0] * inv, of[dt][4 * rg + 1] * inv);
      o2[1] = pk_bf16(of[dt][4 * rg + 2] * inv, of[dt][4 * rg + 3] * inv);
      *(u32x2*)(Xa + qrow * 1024 + h * 64 + dt * 32 + rg * 8 + hi * 4) = o2;
    }
}

// ---------------- launch ----------------
extern "C" void kernel_launch(void* const* d_in, const int* in_sizes, int n_in,
                              void* d_out, int out_size, void* d_ws, size_t ws_size,
                              hipStream_t stream) {
  const float* q  = (const float*)d_in[0];
  const float* k  = (const float*)d_in[1];
  const float* v  = (const float*)d_in[2];
  const float* Wq = (const float*)d_in[3];
  const float* bq = (const float*)d_in[4];
  const float* Wk = (const float*)d_in[5];
  const float* bk = (const float*)d_in[6];
  const float* Wv = (const float*)d_in[7];
  const float* bv = (const float*)d_in[8];
  const float* Wo = (const float*)d_in[9];
  const float* bo = (const float*)d_in[10];

  char* ws = (char*)d_ws;
  const size_t MB = 1024ull * 1024ull;
  u16* wqb = (u16*)(ws + 0 * MB);
  u16* wkb = (u16*)(ws + 2 * MB);
  u16* wvb = (u16*)(ws + 4 * MB);
  u16* wob = (u16*)(ws + 6 * MB);
  u16* xq  = (u16*)(ws + 8 * MB);   // 16MB; reused as Xa after qkv_gemm
  u16* xk  = (u16*)(ws + 24 * MB);  // 16MB
  u16* xv  = (u16*)(ws + 40 * MB);  // 16MB
  u16* Qp  = (u16*)(ws + 56 * MB);  // 16MB, pre-scaled by SC
  u16* Kp  = (u16*)(ws + 72 * MB);  // 16MB
  u16* Vt  = (u16*)(ws + 88 * MB);  // 16MB, dedicated (z=1 reads xk concurrently)
  u16* Xa  = xq;                    // written by attn (xq dead by then)

  cvt_all<<<28672, 256, 0, stream>>>(q, k, v, Wq, Wk, Wv, Wo,
                                     xq, xk, xv, wqb, wkb, wvb, wob);

  const float SC = 0.125f * 1.44269504f;  // head scale * log2(e)
  qkv_gemm<<<dim3(64, 4, 3), 256, 0, stream>>>(xq, xk, xv, wqb, wkb, wvb,
                                               bq, bk, bv, Qp, Kp, Vt, SC);

  attn_fwd<<<dim3(8, 64), 512, 0, stream>>>(Qp, Kp, Vt, Xa);

  o_gemm<<<dim3(64, 4), 256, 0, stream>>>(Xa, wob, bo, (float*)d_out);
}